// Round 19
// baseline (227.371 us; speedup 1.0000x reference)
//
#include <hip/hip_runtime.h>

#define NGRID 65160          // 181*360 grid nodes
#define NMESH 40962
#define NTOT  (NGRID + NMESH) // 106122
#define ZROW  NTOT           // phantom zero row index (dummy edges)
#define CIN   69
#define KPAD1 96
#define HID   256
#define HH    181
#define WWID  360
#define SCAN_BS 1024
#define NBLK_SCAN ((NTOT + SCAN_BS - 1) / SCAN_BS)   // 104

#define NT1TILES ((NTOT + 63) / 64)    // 1659
#define NT1PAD   (NT1TILES * 64)
#define NT2TILES ((NMESH + 63) / 64)   // 641
#define NT2PAD   (NT2TILES * 64)

#define TXBLKS  ((NGRID + 63) / 64)    // 1019 transpose blocks
#define DEGBLKS ((NTOT + 255) / 256)   // 415 deg-init blocks

// packed f16 weight regions (f16 elements): W1 (96 rows) | Wc (256 rows)
#define W1OFF  0
#define WCOFF  (96 * 256)
#define WALLK  (96 + 256)

typedef float f32x4 __attribute__((ext_vector_type(4)));
typedef _Float16 f16;
typedef _Float16 f16x2 __attribute__((ext_vector_type(2)));
typedef _Float16 f16x4 __attribute__((ext_vector_type(4)));
typedef _Float16 f16x8 __attribute__((ext_vector_type(8)));

// tanh-form GELU via sigmoid: 0.5v(1+tanh(u)) = v*sigmoid(2u); max err vs exact ~3e-4
__device__ __forceinline__ float gelu_fast(float v) {
    float u = v * fmaf(v * v, 0.07135481283f, 1.5957691216f);
    return v * __builtin_amdgcn_rcpf(1.0f + __expf(-u));
}

// ------- mega kernel: transpose x | deg/cnt init | epk dummy fill | phantom zeros --
__global__ __launch_bounds__(256) void transpose_x(const float* __restrict__ x,
                                                   f16* __restrict__ h0g,
                                                   float* __restrict__ deg,
                                                   int* __restrict__ cnt,
                                                   int2* __restrict__ epk,
                                                   unsigned* __restrict__ h0z,
                                                   unsigned* __restrict__ Afz,
                                                   int padmax) {
    int b = blockIdx.x;
    if (b >= TXBLKS) {
        int r = b - TXBLKS;
        if (r < DEGBLKS) {
            int i = r * 256 + threadIdx.x;
            if (i < NTOT) { deg[i] = 1.0f; cnt[i] = 0; }
        } else {
            int fb = r - DEGBLKS;
            int nfill = (padmax + 255) / 256;
            if (fb < nfill) {
                int i = fb * 256 + threadIdx.x;
                if (i < padmax) epk[i] = make_int2(ZROW, 0);
            } else {   // last block: phantom zero rows
                if (threadIdx.x < 48)  h0z[threadIdx.x] = 0u;   // 96 f16
                if (threadIdx.x < 128) Afz[threadIdx.x] = 0u;   // 256 f16
            }
        }
        return;
    }
    __shared__ float tile[96][65];
    int s0 = b * 64;
    int t = threadIdx.x;
#pragma unroll
    for (int i = 0; i < 24; ++i) {
        int idx = t + i * 256;
        int c = idx >> 6, s = idx & 63;
        int gs = s0 + s;
        float v = 0.f;
        if (c < CIN && gs < NGRID) v = x[(size_t)c * NGRID + gs];
        tile[c][s] = v;
    }
    __syncthreads();
#pragma unroll
    for (int i = 0; i < 12; ++i) {
        int idx = t + i * 256;
        int r = idx / 48, u = idx % 48;
        int gr = s0 + r;
        if (gr < NGRID) {
            f16x2 p;
            p.x = (f16)tile[u * 2 + 0][r];
            p.y = (f16)tile[u * 2 + 1][r];
            ((f16x2*)h0g)[(size_t)gr * 48 + u] = p;
        }
    }
}

// ---------------- mesh part of h0: bilinear4 gather from transposed grid ----------
__global__ __launch_bounds__(256) void mesh_interp(const f16* __restrict__ h0g,
                                                   const int* __restrict__ Lat,
                                                   const int* __restrict__ Lon,
                                                   f16* __restrict__ h0m) {
    int t = blockIdx.x * 256 + threadIdx.x;
    if (t >= NMESH * 48) return;
    int j = t / 48, u = t % 48;
    int la = Lat[j] - 1;   // 0..720
    int lo = Lon[j] - 1;   // 0..1439
    const f16x2* g = (const f16x2*)h0g;
    f16x2 o;
    if (la == 720) {
        o = g[(size_t)(180 * WWID) * 48 + u];   // pole: x[c, -1, 0]
    } else {
        float sh = fmaxf((la + 0.5f) * 0.25f - 0.5f, 0.0f);
        int i0 = min((int)sh, HH - 2);
        int i1 = min(i0 + 1, HH - 2);
        float wh = sh - (float)i0;
        float sw = fmaxf((lo + 0.5f) * 0.25f - 0.5f, 0.0f);
        int j0 = min((int)sw, WWID - 1);
        int j1 = min(j0 + 1, WWID - 1);
        float ww = sw - (float)j0;
        f16x2 v00 = g[(size_t)(i0 * WWID + j0) * 48 + u];
        f16x2 v10 = g[(size_t)(i1 * WWID + j0) * 48 + u];
        f16x2 v01 = g[(size_t)(i0 * WWID + j1) * 48 + u];
        f16x2 v11 = g[(size_t)(i1 * WWID + j1) * 48 + u];
        float ax = (float)v00.x + ((float)v10.x - (float)v00.x) * wh;
        float ay = (float)v00.y + ((float)v10.y - (float)v00.y) * wh;
        float bx = (float)v01.x + ((float)v11.x - (float)v01.x) * wh;
        float by = (float)v01.y + ((float)v11.y - (float)v01.y) * wh;
        o.x = (f16)(ax + (bx - ax) * ww);
        o.y = (f16)(ay + (by - ay) * ww);
    }
    ((f16x2*)h0m)[(size_t)j * 48 + u] = o;
}

// ---------------- degree scatter ----------------
__global__ void deg_scatter(const int* __restrict__ ei, float* __restrict__ deg, int E) {
    int e = blockIdx.x * 256 + threadIdx.x;
    if (e < E) atomicAdd(&deg[ei[E + e]], 1.0f);
}

// --------- exclusive scan of PADDED in-degree -> CSR offsets (+dinv) ---------------
__global__ __launch_bounds__(SCAN_BS) void scan1(const float* __restrict__ deg,
                                                 float* __restrict__ dinv,
                                                 int* __restrict__ off, int* __restrict__ bsum) {
    __shared__ int s[SCAN_BS];
    int t = threadIdx.x;
    int i = blockIdx.x * SCAN_BS + t;
    int v = (i < NTOT) ? ((int)deg[i] - 1) : 0;
    int vp = (v + 3) & ~3;                    // padded to multiple of 4
    if (i < NTOT) dinv[i] = 1.0f / sqrtf((float)(v + 1));
    s[t] = vp; __syncthreads();
    for (int d = 1; d < SCAN_BS; d <<= 1) {
        int x = (t >= d) ? s[t - d] : 0;
        __syncthreads();
        s[t] += x;
        __syncthreads();
    }
    if (i < NTOT) off[i] = s[t] - vp;         // exclusive (padded)
    if (t == SCAN_BS - 1) bsum[blockIdx.x] = s[t];
}
// scan3 with scan2 merged: every block locally scans the 104 block sums
__global__ __launch_bounds__(SCAN_BS) void scan3(int* __restrict__ off, const int* __restrict__ bsum) {
    __shared__ int s[128];
    int t = threadIdx.x;
    if (t < 128) s[t] = (t < NBLK_SCAN) ? bsum[t] : 0;
    __syncthreads();
    for (int d = 1; d < 128; d <<= 1) {
        int x = 0;
        if (t < 128 && t >= d) x = s[t - d];
        __syncthreads();
        if (t < 128) s[t] += x;
        __syncthreads();
    }
    int base = (blockIdx.x == 0) ? 0 : s[blockIdx.x - 1];   // exclusive prefix
    int i = blockIdx.x * SCAN_BS + t;
    if (i < NTOT) off[i] += base;
}

// ---------------- CSR fill: packed (src, weight) over padded slots ----------------
__global__ void csr_fill(const int* __restrict__ ei, const float* __restrict__ dinv,
                         const int* __restrict__ off, int* __restrict__ cnt,
                         int2* __restrict__ epk, int E) {
    int e = blockIdx.x * 256 + threadIdx.x;
    if (e >= E) return;
    int s = ei[e], d = ei[E + e];
    int pos = off[d] + atomicAdd(&cnt[d], 1);
    epk[pos] = make_int2(s, __float_as_int(dinv[s] * dinv[d]));
}

// ---------------- small fp32 GEMM: M1[256][256] = Wl @ Wl1 (weight collapse) ------
__global__ __launch_bounds__(256) void wgemm(const float* __restrict__ A,
                                             const float* __restrict__ B,
                                             float* __restrict__ C) {
    __shared__ float As[16][68];
    __shared__ float Bs[16][64];
    int r0 = blockIdx.y * 64, c0 = blockIdx.x * 64;
    int t = threadIdx.x;
    int tr = t >> 4, tc = t & 15;
    float acc[4][4] = {};
    for (int kk = 0; kk < 256; kk += 16) {
#pragma unroll
        for (int i = 0; i < 4; ++i) {
            int idx = t + i * 256;
            int r = idx >> 4, k = idx & 15;
            As[k][r] = A[(size_t)(r0 + r) * 256 + kk + k];
        }
#pragma unroll
        for (int i = 0; i < 4; ++i) {
            int idx = t + i * 256;
            int k = idx >> 6, c = idx & 63;
            Bs[k][c] = B[(size_t)(kk + k) * 256 + c0 + c];
        }
        __syncthreads();
#pragma unroll
        for (int k = 0; k < 16; ++k) {
            float a[4], b[4];
#pragma unroll
            for (int i = 0; i < 4; ++i) a[i] = As[k][tr * 4 + i];
#pragma unroll
            for (int j = 0; j < 4; ++j) b[j] = Bs[k][tc * 4 + j];
#pragma unroll
            for (int i = 0; i < 4; ++i)
#pragma unroll
                for (int j = 0; j < 4; ++j) acc[i][j] = fmaf(a[i], b[j], acc[i][j]);
        }
        __syncthreads();
    }
#pragma unroll
    for (int i = 0; i < 4; ++i)
#pragma unroll
        for (int j = 0; j < 4; ++j)
            C[(size_t)(r0 + tr * 4 + i) * 256 + c0 + tc * 4 + j] = acc[i][j];
}

// ------ finish weights: Wc = W2@M1 packed directly into wp | W1 pack | bc ---------
__global__ __launch_bounds__(256) void finish_w(const float* __restrict__ W2,
                                                const float* __restrict__ M1,
                                                const float* __restrict__ W1,
                                                const float* __restrict__ b2,
                                                const float* __restrict__ bl,
                                                const float* __restrict__ Wl1,
                                                const float* __restrict__ bl1,
                                                f16* __restrict__ wp,
                                                float* __restrict__ bc) {
    int b = blockIdx.x;
    int t = threadIdx.x;
    if (b < 16) {
        __shared__ float As[16][68];
        __shared__ float Bs[16][64];
        int r0 = (b >> 2) * 64, c0 = (b & 3) * 64;
        int tr = t >> 4, tc = t & 15;
        float acc[4][4] = {};
        for (int kk = 0; kk < 256; kk += 16) {
#pragma unroll
            for (int i = 0; i < 4; ++i) {
                int idx = t + i * 256;
                int r = idx >> 4, k = idx & 15;
                As[k][r] = W2[(size_t)(r0 + r) * 256 + kk + k];
            }
#pragma unroll
            for (int i = 0; i < 4; ++i) {
                int idx = t + i * 256;
                int k = idx >> 6, c = idx & 63;
                Bs[k][c] = M1[(size_t)(kk + k) * 256 + c0 + c];
            }
            __syncthreads();
#pragma unroll
            for (int k = 0; k < 16; ++k) {
                float a[4], bb[4];
#pragma unroll
                for (int i = 0; i < 4; ++i) a[i] = As[k][tr * 4 + i];
#pragma unroll
                for (int j = 0; j < 4; ++j) bb[j] = Bs[k][tc * 4 + j];
#pragma unroll
                for (int i = 0; i < 4; ++i)
#pragma unroll
                    for (int j = 0; j < 4; ++j) acc[i][j] = fmaf(a[i], bb[j], acc[i][j]);
            }
            __syncthreads();
        }
#pragma unroll
        for (int i = 0; i < 4; ++i) {
            int kl = r0 + tr * 4 + i;                     // logical Wc row
            int ks = ((kl & 15) << 4) | (kl >> 4);        // storage row
#pragma unroll
            for (int j = 0; j < 4; ++j) {
                int c = c0 + tc * 4 + j;
                size_t idx = WCOFF + ((((size_t)(ks >> 3)) * HID + c) << 3) + (ks & 7);
                wp[idx] = (f16)acc[i][j];
            }
        }
    } else if (b < 112) {
        int e = (b - 16) * 256 + t;                       // 0..24575
        int kg = e >> 8, c = e & 255;
        float v = (kg < CIN) ? W1[(size_t)kg * HID + c] : 0.f;
        size_t idx = W1OFF + ((((size_t)(kg >> 3)) * HID + c) << 3) + (kg & 7);
        wp[idx] = (f16)v;
    } else {
        int c = t;
        float acc = bl1[c];
        for (int j = 0; j < 256; ++j) {
            acc = fmaf(b2[j], M1[(size_t)j * 256 + c], acc);
            acc = fmaf(bl[j], Wl1[(size_t)j * 256 + c], acc);
        }
        bc[c] = acc;
    }
}

// ------- agg1: weighted gather, padded lists (no tail); P0 tiles [64][96] swizzled -
__global__ __launch_bounds__(256) void agg1(const f16* __restrict__ h0,
                                            const float* __restrict__ deg,
                                            const float* __restrict__ dinv,
                                            const int* __restrict__ off,
                                            const int2* __restrict__ epk,
                                            f16* __restrict__ P0) {
    int wv = (blockIdx.x * 256 + threadIdx.x) >> 6;
    if (wv >= NT1PAD) return;
    int lane = threadIdx.x & 63;
    if (lane >= 48) return;
    int r = wv & 63, tile = wv >> 6;
    char* dst = (char*)P0 + (size_t)tile * 12288 + ((r * 192 + lane * 4) ^ ((r & 7) << 4));
    if (wv >= NTOT) { *(unsigned*)dst = 0u; return; }
    int d = wv;
    const f16x2* g = (const f16x2*)h0;
    float dv = dinv[d];
    float w2 = dv * dv;
    f16x2 v = g[(size_t)d * 48 + lane];
    float ax = w2 * (float)v.x;
    float ay = w2 * (float)v.y;
    const int2* ep = epk + off[d];
    int np = (((int)deg[d] - 1) + 3) & ~3;     // padded count, multiple of 4
    for (int p = 0; p < np; p += 4) {
        int2 e0 = ep[p], e1 = ep[p + 1], e2 = ep[p + 2], e3 = ep[p + 3];
        f16x2 u0 = g[(size_t)e0.x * 48 + lane];
        f16x2 u1 = g[(size_t)e1.x * 48 + lane];
        f16x2 u2 = g[(size_t)e2.x * 48 + lane];
        f16x2 u3 = g[(size_t)e3.x * 48 + lane];
        float w0 = __int_as_float(e0.y), w1 = __int_as_float(e1.y);
        float w2b = __int_as_float(e2.y), w3 = __int_as_float(e3.y);
        ax = fmaf(w0, (float)u0.x, ax); ay = fmaf(w0, (float)u0.y, ay);
        ax = fmaf(w1, (float)u1.x, ax); ay = fmaf(w1, (float)u1.y, ay);
        ax = fmaf(w2b, (float)u2.x, ax); ay = fmaf(w2b, (float)u2.y, ay);
        ax = fmaf(w3, (float)u3.x, ax); ay = fmaf(w3, (float)u3.y, ay);
    }
    f16x2 o; o.x = (f16)ax; o.y = (f16)ay;
    *(f16x2*)dst = o;
}

// ------- agg2: weighted gather, padded lists; P2 tiles [64][256] f16 swizzled -----
__global__ __launch_bounds__(256) void agg2(const f16* __restrict__ A,
                                            const float* __restrict__ deg,
                                            const float* __restrict__ dinv,
                                            const int* __restrict__ off,
                                            const int2* __restrict__ epk,
                                            f16* __restrict__ P2) {
    int wv = (blockIdx.x * 256 + threadIdx.x) >> 6;
    if (wv >= NT2PAD) return;
    int lane = threadIdx.x & 63;
    int r = wv & 63, tile = wv >> 6;
    char* dst = (char*)P2 + (size_t)tile * 32768 + ((r * 512 + lane * 8) ^ ((r & 7) << 4));
    if (wv >= NMESH) { *(unsigned long long*)dst = 0ull; return; }
    int d = NGRID + wv;
    const f16x4* g = (const f16x4*)A;
    float dv = dinv[d];
    float w2 = dv * dv;
    f16x4 v = g[(size_t)d * 64 + lane];
    float4 acc;
    acc.x = w2 * (float)v.x; acc.y = w2 * (float)v.y;
    acc.z = w2 * (float)v.z; acc.w = w2 * (float)v.w;
    const int2* ep = epk + off[d];
    int np = (((int)deg[d] - 1) + 3) & ~3;
    for (int p = 0; p < np; p += 4) {
        int2 e0 = ep[p], e1 = ep[p + 1], e2 = ep[p + 2], e3 = ep[p + 3];
        f16x4 u0 = g[(size_t)e0.x * 64 + lane];
        f16x4 u1 = g[(size_t)e1.x * 64 + lane];
        f16x4 u2 = g[(size_t)e2.x * 64 + lane];
        f16x4 u3 = g[(size_t)e3.x * 64 + lane];
        float w0 = __int_as_float(e0.y), w1 = __int_as_float(e1.y);
        float w2b = __int_as_float(e2.y), w3 = __int_as_float(e3.y);
        acc.x = fmaf(w0, (float)u0.x, acc.x); acc.y = fmaf(w0, (float)u0.y, acc.y);
        acc.z = fmaf(w0, (float)u0.z, acc.z); acc.w = fmaf(w0, (float)u0.w, acc.w);
        acc.x = fmaf(w1, (float)u1.x, acc.x); acc.y = fmaf(w1, (float)u1.y, acc.y);
        acc.z = fmaf(w1, (float)u1.z, acc.z); acc.w = fmaf(w1, (float)u1.w, acc.w);
        acc.x = fmaf(w2b, (float)u2.x, acc.x); acc.y = fmaf(w2b, (float)u2.y, acc.y);
        acc.z = fmaf(w2b, (float)u2.z, acc.z); acc.w = fmaf(w2b, (float)u2.w, acc.w);
        acc.x = fmaf(w3, (float)u3.x, acc.x); acc.y = fmaf(w3, (float)u3.y, acc.y);
        acc.z = fmaf(w3, (float)u3.z, acc.z); acc.w = fmaf(w3, (float)u3.w, acc.w);
    }
    f16x4 o;
    o.x = (f16)acc.x; o.y = (f16)acc.y; o.z = (f16)acc.z; o.w = (f16)acc.w;
    *(f16x4*)dst = o;
}

// ---------------- layer-1 GEMM: one wave per 16-row x 128-col stripe ---------------
// Af = gelu(P0 @ W1 + b1), stored sigma256-permuted: position p = l15*16 + cb.
__global__ __launch_bounds__(256) void gemm1_f16(const f16* __restrict__ P0,
                                                 const f16* __restrict__ wp,
                                                 const float* __restrict__ bias,
                                                 f16* __restrict__ Af) {
    const int wid = (blockIdx.x * 256 + threadIdx.x) >> 6;   // stripe id
    const int lane = threadIdx.x & 63;
    const int l15 = lane & 15, l4 = lane >> 4;
    const int tile = wid >> 3;
    const int rb = (wid >> 1) & 3;      // 16-row block within tile
    const int ch = wid & 1;             // channel half (8 cb)
    if (tile >= NT1TILES) return;

    // A fragments straight from P0's swizzled global tile
    f16x8 a[3];
    {
        const char* base = (const char*)P0 + (size_t)tile * 12288;
        int r = rb * 16 + l15;
#pragma unroll
        for (int ks = 0; ks < 3; ++ks) {
            int byte = r * 192 + (ks * 32 + l4 * 8) * 2;
            a[ks] = *(const f16x8*)(base + (byte ^ ((r & 7) << 4)));
        }
    }

    f32x4 acc[8];
#pragma unroll
    for (int j = 0; j < 8; ++j) acc[j] = (f32x4)0.f;
#pragma unroll
    for (int j = 0; j < 8; ++j) {
        int c = (ch * 8 + j) * 16 + l15;
#pragma unroll
        for (int ks = 0; ks < 3; ++ks) {
            size_t o = ((((size_t)ks << 2) + l4) * HID + c) << 3;
            f16x8 w = *(const f16x8*)(wp + W1OFF + o);
            acc[j] = __builtin_amdgcn_mfma_f32_16x16x32_f16(a[ks], w, acc[j], 0, 0, 0);
        }
    }

    float bv[8];
#pragma unroll
    for (int j = 0; j < 8; ++j) bv[j] = bias[(ch * 8 + j) * 16 + l15];

    // epilogue: 4 rows/lane; 8 values per row stored contiguously at p = l15*16 + ch*8
    const int gr0 = tile * 64 + rb * 16 + l4 * 4;
#pragma unroll
    for (int reg = 0; reg < 4; ++reg) {
        int gr = gr0 + reg;
        if (gr < NTOT) {
            f16x8 o;
#pragma unroll
            for (int j = 0; j < 8; ++j)
                o[j] = (f16)gelu_fast(acc[j][reg] + bv[j]);
            *(f16x8*)(Af + (size_t)gr * HID + l15 * 16 + ch * 8) = o;
        }
    }
}

// ------- final: one wave per 64-channel x 32-node stripe, no LDS, no barriers ------
// out(256 x NMESH) = gelu(Wc^T @ P2^T + bc); B-fragments read straight from P2's
// swizzled global tiles (8 waves share each 32KB tile -> L2-hot).
__global__ __launch_bounds__(256) void final_k(const f16* __restrict__ P2,
                                               const f16* __restrict__ wp,
                                               const float* __restrict__ bc,
                                               float* __restrict__ out) {
    const int wid = (blockIdx.x * 256 + threadIdx.x) >> 6;
    const int lane = threadIdx.x & 63;
    const int l15 = lane & 15, l4 = lane >> 4;
    const int tile = wid >> 3;
    const int cw = (wid & 3) * 64;          // channel block
    const int jh = (wid >> 2) & 1;          // mesh half within tile
    if (tile >= NT2TILES) return;
    const int row0 = tile * 64 + jh * 32;
    const char* base = (const char*)P2 + (size_t)tile * 32768;

    f32x4 acc[4][2] = {};
#pragma unroll
    for (int ks = 0; ks < 256; ks += 32) {
        f16x8 w[4], p[2];
#pragma unroll
        for (int mb = 0; mb < 4; ++mb) {
            int c = cw + mb * 16 + l15;
            size_t off = ((((size_t)ks >> 3) + l4) * HID + c) << 3;
            w[mb] = *(const f16x8*)(wp + WCOFF + off);
        }
#pragma unroll
        for (int jb = 0; jb < 2; ++jb) {
            int r = jh * 32 + jb * 16 + l15;
            int byte = r * 512 + (ks + l4 * 8) * 2;
            p[jb] = *(const f16x8*)(base + (byte ^ ((r & 7) << 4)));
        }
#pragma unroll
        for (int mb = 0; mb < 4; ++mb)
#pragma unroll
            for (int jb = 0; jb < 2; ++jb)
                acc[mb][jb] = __builtin_amdgcn_mfma_f32_16x16x32_f16(w[mb], p[jb], acc[mb][jb], 0, 0, 0);
    }
    const bool full = (row0 + 32 <= NMESH);
#pragma unroll
    for (int mb = 0; mb < 4; ++mb) {
#pragma unroll
        for (int r = 0; r < 4; ++r) {
            int c = cw + mb * 16 + l4 * 4 + r;
            float bv = bc[c];
            float* orow = out + (size_t)c * NMESH + row0;
#pragma unroll
            for (int jb = 0; jb < 2; ++jb) {
                int j = jb * 16 + l15;
                float v = gelu_fast(acc[mb][jb][r] + bv);
                if (full || row0 + j < NMESH) orow[j] = v;
            }
        }
    }
}

extern "C" void kernel_launch(void* const* d_in, const int* in_sizes, int n_in,
                              void* d_out, int out_size, void* d_ws, size_t ws_size,
                              hipStream_t stream) {
    const float* x   = (const float*)d_in[0];
    const int*   ei  = (const int*)d_in[1];
    const int*   Lat = (const int*)d_in[2];
    const int*   Lon = (const int*)d_in[3];
    const float* W1  = (const float*)d_in[4];
    const float* b1  = (const float*)d_in[5];
    const float* W2  = (const float*)d_in[6];
    const float* b2  = (const float*)d_in[7];
    const float* Wl  = (const float*)d_in[8];
    const float* bl  = (const float*)d_in[9];
    const float* Wl1 = (const float*)d_in[10];
    const float* bl1 = (const float*)d_in[11];
    float* out = (float*)d_out;
    const int E = in_sizes[1] / 2;
    const int padmax = E + 3 * NTOT + 4;             // upper bound on padded edges
    const int nfill = (padmax + 255) / 256;

    // d_out scratch: h0 fp16 (NTOT+1 rows incl. phantom) + epk; final_k overwrites.
    f16*   h0  = (f16*)d_out;                        // (NTOT+1)*96 fp16
    int2*  epk = (int2*)((char*)d_out + (size_t)(NTOT + 1) * KPAD1 * 2);

    f16*   P0   = (f16*)d_ws;                        // NT1TILES*6144 f16 (swizzled tiles)
    f16*   Af   = P0 + (size_t)NT1TILES * 6144;      // (NTOT+1)*256 f16 (sigma256 cols)
    f16*   P2   = Af + (size_t)(NTOT + 1) * HID;     // NT2TILES*16384 f16 (swizzled tiles)
    float* deg  = (float*)(P2 + (size_t)NT2TILES * 16384);
    float* dinv = deg + NTOT;
    int*   off  = (int*)(dinv + NTOT);
    int*   cnt  = off + NTOT;
    int*   bsum = cnt + NTOT;                        // 128
    float* M1   = (float*)(bsum + 128);              // 256*256 (Wl@Wl1)
    float* bc   = M1 + HID * HID;                    // 256
    f16*   wp   = (f16*)(bc + HID);                  // WALLK*256 f16 packed

    // 1. mega: transpose x | deg/cnt init | epk dummy fill | phantom zero rows
    transpose_x<<<TXBLKS + DEGBLKS + nfill + 1, 256, 0, stream>>>(
        x, h0, deg, cnt, epk,
        (unsigned*)(h0 + (size_t)NTOT * KPAD1),
        (unsigned*)(Af + (size_t)NTOT * HID), padmax);
    mesh_interp<<<(NMESH * 48 + 255) / 256, 256, 0, stream>>>(h0, Lat, Lon,
                                                              h0 + (size_t)NGRID * KPAD1);

    // 2. degree / norm / padded CSR
    deg_scatter<<<(E + 255) / 256, 256, 0, stream>>>(ei, deg, E);
    scan1<<<NBLK_SCAN, SCAN_BS, 0, stream>>>(deg, dinv, off, bsum);
    scan3<<<NBLK_SCAN, SCAN_BS, 0, stream>>>(off, bsum);
    csr_fill<<<(E + 255) / 256, 256, 0, stream>>>(ei, dinv, off, cnt, epk, E);

    // 2b. weight collapse: M1 = Wl@Wl1; then Wc packed + W1 packed + bc in one kernel
    dim3 gW(4, 4);
    wgemm<<<gW, 256, 0, stream>>>(Wl, Wl1, M1);
    finish_w<<<113, 256, 0, stream>>>(W2, M1, W1, b2, bl, Wl1, bl1, wp, bc);

    // 3. layer 1: padded weighted aggregate -> P0, then wave-per-stripe GEMM
    agg1<<<(int)(((long long)NT1PAD * 64 + 255) / 256), 256, 0, stream>>>(
        h0, deg, dinv, off, epk, P0);
    gemm1_f16<<<(NT1TILES * 8 * 64 + 255) / 256, 256, 0, stream>>>(P0, wp, b1, Af);

    // 4. layer 2 aggregation (mesh dsts only) -> P2
    agg2<<<(int)(((long long)NT2PAD * 64 + 255) / 256), 256, 0, stream>>>(
        Af, deg, dinv, off, epk, P2);

    // 5. collapsed tail: wave-per-stripe GEMM, written directly transposed
    final_k<<<(NT2TILES * 8 * 64 + 255) / 256, 256, 0, stream>>>(P2, wp, bc, out);
}

// Round 20
// 223.164 us; speedup vs baseline: 1.0189x; 1.0189x over previous
//
#include <hip/hip_runtime.h>

#define NGRID 65160          // 181*360 grid nodes
#define NMESH 40962
#define NTOT  (NGRID + NMESH) // 106122
#define ZROW  NTOT           // phantom zero row index (dummy edges)
#define CIN   69
#define KPAD1 96
#define HID   256
#define HH    181
#define WWID  360
#define SCAN_BS 1024
#define NBLK_SCAN ((NTOT + SCAN_BS - 1) / SCAN_BS)   // 104

#define NT1TILES ((NTOT + 63) / 64)    // 1659
#define NT1PAD   (NT1TILES * 64)
#define NT2TILES ((NMESH + 63) / 64)   // 641
#define NT2PAD   (NT2TILES * 64)

#define TXBLKS  ((NGRID + 63) / 64)    // 1019 transpose blocks
#define DEGBLKS ((NTOT + 255) / 256)   // 415 deg-init blocks

// packed f16 weight regions (f16 elements): W1 (96 rows) | Wc (256 rows)
#define W1OFF  0
#define WCOFF  (96 * 256)
#define WALLK  (96 + 256)

typedef float f32x4 __attribute__((ext_vector_type(4)));
typedef _Float16 f16;
typedef _Float16 f16x2 __attribute__((ext_vector_type(2)));
typedef _Float16 f16x4 __attribute__((ext_vector_type(4)));
typedef _Float16 f16x8 __attribute__((ext_vector_type(8)));

// tanh-form GELU via sigmoid: 0.5v(1+tanh(u)) = v*sigmoid(2u); max err vs exact ~3e-4
__device__ __forceinline__ float gelu_fast(float v) {
    float u = v * fmaf(v * v, 0.07135481283f, 1.5957691216f);
    return v * __builtin_amdgcn_rcpf(1.0f + __expf(-u));
}

// ------- mega kernel: transpose x | deg/cnt init | epk dummy fill | phantom zeros --
__global__ __launch_bounds__(256) void transpose_x(const float* __restrict__ x,
                                                   f16* __restrict__ h0g,
                                                   float* __restrict__ deg,
                                                   int* __restrict__ cnt,
                                                   int2* __restrict__ epk,
                                                   unsigned* __restrict__ h0z,
                                                   unsigned* __restrict__ Afz,
                                                   int padmax) {
    int b = blockIdx.x;
    if (b >= TXBLKS) {
        int r = b - TXBLKS;
        if (r < DEGBLKS) {
            int i = r * 256 + threadIdx.x;
            if (i < NTOT) { deg[i] = 1.0f; cnt[i] = 0; }
        } else {
            int fb = r - DEGBLKS;
            int nfill = (padmax + 255) / 256;
            if (fb < nfill) {
                int i = fb * 256 + threadIdx.x;
                if (i < padmax) epk[i] = make_int2(ZROW, 0);
            } else {   // last block: phantom zero rows
                if (threadIdx.x < 48)  h0z[threadIdx.x] = 0u;   // 96 f16
                if (threadIdx.x < 128) Afz[threadIdx.x] = 0u;   // 256 f16
            }
        }
        return;
    }
    __shared__ float tile[96][65];
    int s0 = b * 64;
    int t = threadIdx.x;
#pragma unroll
    for (int i = 0; i < 24; ++i) {
        int idx = t + i * 256;
        int c = idx >> 6, s = idx & 63;
        int gs = s0 + s;
        float v = 0.f;
        if (c < CIN && gs < NGRID) v = x[(size_t)c * NGRID + gs];
        tile[c][s] = v;
    }
    __syncthreads();
#pragma unroll
    for (int i = 0; i < 12; ++i) {
        int idx = t + i * 256;
        int r = idx / 48, u = idx % 48;
        int gr = s0 + r;
        if (gr < NGRID) {
            f16x2 p;
            p.x = (f16)tile[u * 2 + 0][r];
            p.y = (f16)tile[u * 2 + 1][r];
            ((f16x2*)h0g)[(size_t)gr * 48 + u] = p;
        }
    }
}

// ---------------- mesh part of h0: bilinear4 gather from transposed grid ----------
__global__ __launch_bounds__(256) void mesh_interp(const f16* __restrict__ h0g,
                                                   const int* __restrict__ Lat,
                                                   const int* __restrict__ Lon,
                                                   f16* __restrict__ h0m) {
    int t = blockIdx.x * 256 + threadIdx.x;
    if (t >= NMESH * 48) return;
    int j = t / 48, u = t % 48;
    int la = Lat[j] - 1;   // 0..720
    int lo = Lon[j] - 1;   // 0..1439
    const f16x2* g = (const f16x2*)h0g;
    f16x2 o;
    if (la == 720) {
        o = g[(size_t)(180 * WWID) * 48 + u];   // pole: x[c, -1, 0]
    } else {
        float sh = fmaxf((la + 0.5f) * 0.25f - 0.5f, 0.0f);
        int i0 = min((int)sh, HH - 2);
        int i1 = min(i0 + 1, HH - 2);
        float wh = sh - (float)i0;
        float sw = fmaxf((lo + 0.5f) * 0.25f - 0.5f, 0.0f);
        int j0 = min((int)sw, WWID - 1);
        int j1 = min(j0 + 1, WWID - 1);
        float ww = sw - (float)j0;
        f16x2 v00 = g[(size_t)(i0 * WWID + j0) * 48 + u];
        f16x2 v10 = g[(size_t)(i1 * WWID + j0) * 48 + u];
        f16x2 v01 = g[(size_t)(i0 * WWID + j1) * 48 + u];
        f16x2 v11 = g[(size_t)(i1 * WWID + j1) * 48 + u];
        float ax = (float)v00.x + ((float)v10.x - (float)v00.x) * wh;
        float ay = (float)v00.y + ((float)v10.y - (float)v00.y) * wh;
        float bx = (float)v01.x + ((float)v11.x - (float)v01.x) * wh;
        float by = (float)v01.y + ((float)v11.y - (float)v01.y) * wh;
        o.x = (f16)(ax + (bx - ax) * ww);
        o.y = (f16)(ay + (by - ay) * ww);
    }
    ((f16x2*)h0m)[(size_t)j * 48 + u] = o;
}

// ---------------- degree scatter ----------------
__global__ void deg_scatter(const int* __restrict__ ei, float* __restrict__ deg, int E) {
    int e = blockIdx.x * 256 + threadIdx.x;
    if (e < E) atomicAdd(&deg[ei[E + e]], 1.0f);
}

// --------- exclusive scan of PADDED in-degree -> CSR offsets (+dinv) ---------------
__global__ __launch_bounds__(SCAN_BS) void scan1(const float* __restrict__ deg,
                                                 float* __restrict__ dinv,
                                                 int* __restrict__ off, int* __restrict__ bsum) {
    __shared__ int s[SCAN_BS];
    int t = threadIdx.x;
    int i = blockIdx.x * SCAN_BS + t;
    int v = (i < NTOT) ? ((int)deg[i] - 1) : 0;
    int vp = (v + 3) & ~3;                    // padded to multiple of 4
    if (i < NTOT) dinv[i] = 1.0f / sqrtf((float)(v + 1));
    s[t] = vp; __syncthreads();
    for (int d = 1; d < SCAN_BS; d <<= 1) {
        int x = (t >= d) ? s[t - d] : 0;
        __syncthreads();
        s[t] += x;
        __syncthreads();
    }
    if (i < NTOT) off[i] = s[t] - vp;         // exclusive (padded)
    if (t == SCAN_BS - 1) bsum[blockIdx.x] = s[t];
}
// scan3 with scan2 merged: every block locally scans the 104 block sums
__global__ __launch_bounds__(SCAN_BS) void scan3(int* __restrict__ off, const int* __restrict__ bsum) {
    __shared__ int s[128];
    int t = threadIdx.x;
    if (t < 128) s[t] = (t < NBLK_SCAN) ? bsum[t] : 0;
    __syncthreads();
    for (int d = 1; d < 128; d <<= 1) {
        int x = 0;
        if (t < 128 && t >= d) x = s[t - d];
        __syncthreads();
        if (t < 128) s[t] += x;
        __syncthreads();
    }
    int base = (blockIdx.x == 0) ? 0 : s[blockIdx.x - 1];   // exclusive prefix
    int i = blockIdx.x * SCAN_BS + t;
    if (i < NTOT) off[i] += base;
}

// ---------------- CSR fill: packed (src, weight) over padded slots ----------------
__global__ void csr_fill(const int* __restrict__ ei, const float* __restrict__ dinv,
                         const int* __restrict__ off, int* __restrict__ cnt,
                         int2* __restrict__ epk, int E) {
    int e = blockIdx.x * 256 + threadIdx.x;
    if (e >= E) return;
    int s = ei[e], d = ei[E + e];
    int pos = off[d] + atomicAdd(&cnt[d], 1);
    epk[pos] = make_int2(s, __float_as_int(dinv[s] * dinv[d]));
}

// ---------------- small fp32 GEMM: M1[256][256] = Wl @ Wl1 (weight collapse) ------
__global__ __launch_bounds__(256) void wgemm(const float* __restrict__ A,
                                             const float* __restrict__ B,
                                             float* __restrict__ C) {
    __shared__ float As[16][68];
    __shared__ float Bs[16][64];
    int r0 = blockIdx.y * 64, c0 = blockIdx.x * 64;
    int t = threadIdx.x;
    int tr = t >> 4, tc = t & 15;
    float acc[4][4] = {};
    for (int kk = 0; kk < 256; kk += 16) {
#pragma unroll
        for (int i = 0; i < 4; ++i) {
            int idx = t + i * 256;
            int r = idx >> 4, k = idx & 15;
            As[k][r] = A[(size_t)(r0 + r) * 256 + kk + k];
        }
#pragma unroll
        for (int i = 0; i < 4; ++i) {
            int idx = t + i * 256;
            int k = idx >> 6, c = idx & 63;
            Bs[k][c] = B[(size_t)(kk + k) * 256 + c0 + c];
        }
        __syncthreads();
#pragma unroll
        for (int k = 0; k < 16; ++k) {
            float a[4], b[4];
#pragma unroll
            for (int i = 0; i < 4; ++i) a[i] = As[k][tr * 4 + i];
#pragma unroll
            for (int j = 0; j < 4; ++j) b[j] = Bs[k][tc * 4 + j];
#pragma unroll
            for (int i = 0; i < 4; ++i)
#pragma unroll
                for (int j = 0; j < 4; ++j) acc[i][j] = fmaf(a[i], b[j], acc[i][j]);
        }
        __syncthreads();
    }
#pragma unroll
    for (int i = 0; i < 4; ++i)
#pragma unroll
        for (int j = 0; j < 4; ++j)
            C[(size_t)(r0 + tr * 4 + i) * 256 + c0 + tc * 4 + j] = acc[i][j];
}

// ------ finish weights: Wc = W2@M1 packed directly into wp | W1 pack | bc ---------
__global__ __launch_bounds__(256) void finish_w(const float* __restrict__ W2,
                                                const float* __restrict__ M1,
                                                const float* __restrict__ W1,
                                                const float* __restrict__ b2,
                                                const float* __restrict__ bl,
                                                const float* __restrict__ Wl1,
                                                const float* __restrict__ bl1,
                                                f16* __restrict__ wp,
                                                float* __restrict__ bc) {
    int b = blockIdx.x;
    int t = threadIdx.x;
    if (b < 16) {
        __shared__ float As[16][68];
        __shared__ float Bs[16][64];
        int r0 = (b >> 2) * 64, c0 = (b & 3) * 64;
        int tr = t >> 4, tc = t & 15;
        float acc[4][4] = {};
        for (int kk = 0; kk < 256; kk += 16) {
#pragma unroll
            for (int i = 0; i < 4; ++i) {
                int idx = t + i * 256;
                int r = idx >> 4, k = idx & 15;
                As[k][r] = W2[(size_t)(r0 + r) * 256 + kk + k];
            }
#pragma unroll
            for (int i = 0; i < 4; ++i) {
                int idx = t + i * 256;
                int k = idx >> 6, c = idx & 63;
                Bs[k][c] = M1[(size_t)(kk + k) * 256 + c0 + c];
            }
            __syncthreads();
#pragma unroll
            for (int k = 0; k < 16; ++k) {
                float a[4], bb[4];
#pragma unroll
                for (int i = 0; i < 4; ++i) a[i] = As[k][tr * 4 + i];
#pragma unroll
                for (int j = 0; j < 4; ++j) bb[j] = Bs[k][tc * 4 + j];
#pragma unroll
                for (int i = 0; i < 4; ++i)
#pragma unroll
                    for (int j = 0; j < 4; ++j) acc[i][j] = fmaf(a[i], bb[j], acc[i][j]);
            }
            __syncthreads();
        }
#pragma unroll
        for (int i = 0; i < 4; ++i) {
            int kl = r0 + tr * 4 + i;                     // logical Wc row
            int ks = ((kl & 15) << 4) | (kl >> 4);        // storage row
#pragma unroll
            for (int j = 0; j < 4; ++j) {
                int c = c0 + tc * 4 + j;
                size_t idx = WCOFF + ((((size_t)(ks >> 3)) * HID + c) << 3) + (ks & 7);
                wp[idx] = (f16)acc[i][j];
            }
        }
    } else if (b < 112) {
        int e = (b - 16) * 256 + t;                       // 0..24575
        int kg = e >> 8, c = e & 255;
        float v = (kg < CIN) ? W1[(size_t)kg * HID + c] : 0.f;
        size_t idx = W1OFF + ((((size_t)(kg >> 3)) * HID + c) << 3) + (kg & 7);
        wp[idx] = (f16)v;
    } else {
        int c = t;
        float acc = bl1[c];
        for (int j = 0; j < 256; ++j) {
            acc = fmaf(b2[j], M1[(size_t)j * 256 + c], acc);
            acc = fmaf(bl[j], Wl1[(size_t)j * 256 + c], acc);
        }
        bc[c] = acc;
    }
}

// ------- agg1: weighted gather, padded lists (no tail); P0 tiles [64][96] swizzled -
__global__ __launch_bounds__(256) void agg1(const f16* __restrict__ h0,
                                            const float* __restrict__ deg,
                                            const float* __restrict__ dinv,
                                            const int* __restrict__ off,
                                            const int2* __restrict__ epk,
                                            f16* __restrict__ P0) {
    int wv = (blockIdx.x * 256 + threadIdx.x) >> 6;
    if (wv >= NT1PAD) return;
    int lane = threadIdx.x & 63;
    if (lane >= 48) return;
    int r = wv & 63, tile = wv >> 6;
    char* dst = (char*)P0 + (size_t)tile * 12288 + ((r * 192 + lane * 4) ^ ((r & 7) << 4));
    if (wv >= NTOT) { *(unsigned*)dst = 0u; return; }
    int d = wv;
    const f16x2* g = (const f16x2*)h0;
    float dv = dinv[d];
    float w2 = dv * dv;
    f16x2 v = g[(size_t)d * 48 + lane];
    float ax = w2 * (float)v.x;
    float ay = w2 * (float)v.y;
    const int2* ep = epk + off[d];
    int np = (((int)deg[d] - 1) + 3) & ~3;     // padded count, multiple of 4
    for (int p = 0; p < np; p += 4) {
        int2 e0 = ep[p], e1 = ep[p + 1], e2 = ep[p + 2], e3 = ep[p + 3];
        f16x2 u0 = g[(size_t)e0.x * 48 + lane];
        f16x2 u1 = g[(size_t)e1.x * 48 + lane];
        f16x2 u2 = g[(size_t)e2.x * 48 + lane];
        f16x2 u3 = g[(size_t)e3.x * 48 + lane];
        float w0 = __int_as_float(e0.y), w1 = __int_as_float(e1.y);
        float w2b = __int_as_float(e2.y), w3 = __int_as_float(e3.y);
        ax = fmaf(w0, (float)u0.x, ax); ay = fmaf(w0, (float)u0.y, ay);
        ax = fmaf(w1, (float)u1.x, ax); ay = fmaf(w1, (float)u1.y, ay);
        ax = fmaf(w2b, (float)u2.x, ax); ay = fmaf(w2b, (float)u2.y, ay);
        ax = fmaf(w3, (float)u3.x, ax); ay = fmaf(w3, (float)u3.y, ay);
    }
    f16x2 o; o.x = (f16)ax; o.y = (f16)ay;
    *(f16x2*)dst = o;
}

// ------- agg2: weighted gather, padded lists; P2 tiles [64][256] f16 swizzled -----
__global__ __launch_bounds__(256) void agg2(const f16* __restrict__ A,
                                            const float* __restrict__ deg,
                                            const float* __restrict__ dinv,
                                            const int* __restrict__ off,
                                            const int2* __restrict__ epk,
                                            f16* __restrict__ P2) {
    int wv = (blockIdx.x * 256 + threadIdx.x) >> 6;
    if (wv >= NT2PAD) return;
    int lane = threadIdx.x & 63;
    int r = wv & 63, tile = wv >> 6;
    char* dst = (char*)P2 + (size_t)tile * 32768 + ((r * 512 + lane * 8) ^ ((r & 7) << 4));
    if (wv >= NMESH) { *(unsigned long long*)dst = 0ull; return; }
    int d = NGRID + wv;
    const f16x4* g = (const f16x4*)A;
    float dv = dinv[d];
    float w2 = dv * dv;
    f16x4 v = g[(size_t)d * 64 + lane];
    float4 acc;
    acc.x = w2 * (float)v.x; acc.y = w2 * (float)v.y;
    acc.z = w2 * (float)v.z; acc.w = w2 * (float)v.w;
    const int2* ep = epk + off[d];
    int np = (((int)deg[d] - 1) + 3) & ~3;
    for (int p = 0; p < np; p += 4) {
        int2 e0 = ep[p], e1 = ep[p + 1], e2 = ep[p + 2], e3 = ep[p + 3];
        f16x4 u0 = g[(size_t)e0.x * 64 + lane];
        f16x4 u1 = g[(size_t)e1.x * 64 + lane];
        f16x4 u2 = g[(size_t)e2.x * 64 + lane];
        f16x4 u3 = g[(size_t)e3.x * 64 + lane];
        float w0 = __int_as_float(e0.y), w1 = __int_as_float(e1.y);
        float w2b = __int_as_float(e2.y), w3 = __int_as_float(e3.y);
        acc.x = fmaf(w0, (float)u0.x, acc.x); acc.y = fmaf(w0, (float)u0.y, acc.y);
        acc.z = fmaf(w0, (float)u0.z, acc.z); acc.w = fmaf(w0, (float)u0.w, acc.w);
        acc.x = fmaf(w1, (float)u1.x, acc.x); acc.y = fmaf(w1, (float)u1.y, acc.y);
        acc.z = fmaf(w1, (float)u1.z, acc.z); acc.w = fmaf(w1, (float)u1.w, acc.w);
        acc.x = fmaf(w2b, (float)u2.x, acc.x); acc.y = fmaf(w2b, (float)u2.y, acc.y);
        acc.z = fmaf(w2b, (float)u2.z, acc.z); acc.w = fmaf(w2b, (float)u2.w, acc.w);
        acc.x = fmaf(w3, (float)u3.x, acc.x); acc.y = fmaf(w3, (float)u3.y, acc.y);
        acc.z = fmaf(w3, (float)u3.z, acc.z); acc.w = fmaf(w3, (float)u3.w, acc.w);
    }
    f16x4 o;
    o.x = (f16)acc.x; o.y = (f16)acc.y; o.z = (f16)acc.z; o.w = (f16)acc.w;
    *(f16x4*)dst = o;
}

// ---------------- layer-1 GEMM: one wave per 16-row x 128-col stripe ---------------
// Af = gelu(P0 @ W1 + b1), stored sigma256-permuted: position p = l15*16 + cb.
__global__ __launch_bounds__(256) void gemm1_f16(const f16* __restrict__ P0,
                                                 const f16* __restrict__ wp,
                                                 const float* __restrict__ bias,
                                                 f16* __restrict__ Af) {
    const int wid = (blockIdx.x * 256 + threadIdx.x) >> 6;   // stripe id
    const int lane = threadIdx.x & 63;
    const int l15 = lane & 15, l4 = lane >> 4;
    const int tile = wid >> 3;
    const int rb = (wid >> 1) & 3;      // 16-row block within tile
    const int ch = wid & 1;             // channel half (8 cb)
    if (tile >= NT1TILES) return;

    // A fragments straight from P0's swizzled global tile
    f16x8 a[3];
    {
        const char* base = (const char*)P0 + (size_t)tile * 12288;
        int r = rb * 16 + l15;
#pragma unroll
        for (int ks = 0; ks < 3; ++ks) {
            int byte = r * 192 + (ks * 32 + l4 * 8) * 2;
            a[ks] = *(const f16x8*)(base + (byte ^ ((r & 7) << 4)));
        }
    }

    f32x4 acc[8];
#pragma unroll
    for (int j = 0; j < 8; ++j) acc[j] = (f32x4)0.f;
#pragma unroll
    for (int j = 0; j < 8; ++j) {
        int c = (ch * 8 + j) * 16 + l15;
#pragma unroll
        for (int ks = 0; ks < 3; ++ks) {
            size_t o = ((((size_t)ks << 2) + l4) * HID + c) << 3;
            f16x8 w = *(const f16x8*)(wp + W1OFF + o);
            acc[j] = __builtin_amdgcn_mfma_f32_16x16x32_f16(a[ks], w, acc[j], 0, 0, 0);
        }
    }

    float bv[8];
#pragma unroll
    for (int j = 0; j < 8; ++j) bv[j] = bias[(ch * 8 + j) * 16 + l15];

    // epilogue: 4 rows/lane; 8 values per row stored contiguously at p = l15*16 + ch*8
    const int gr0 = tile * 64 + rb * 16 + l4 * 4;
#pragma unroll
    for (int reg = 0; reg < 4; ++reg) {
        int gr = gr0 + reg;
        if (gr < NTOT) {
            f16x8 o;
#pragma unroll
            for (int j = 0; j < 8; ++j)
                o[j] = (f16)gelu_fast(acc[j][reg] + bv[j]);
            *(f16x8*)(Af + (size_t)gr * HID + l15 * 16 + ch * 8) = o;
        }
    }
}

// ---------------- final (f16 MFMA): out(256 x NMESH) = gelu(Wc^T @ P2^T + bc) -----
__global__ __launch_bounds__(256) void final_k(const f16* __restrict__ P2,
                                               const f16* __restrict__ wp,
                                               const float* __restrict__ bc,
                                               float* __restrict__ out) {
    __shared__ __align__(16) f16 Ps[64 * 256];  // 32 KB, swizzled tile copy
    const int tile = blockIdx.x;
    const int row0 = tile * 64;                 // mesh-index block
    const int t = threadIdx.x;
    const int lane = t & 63;
    const int wave = t >> 6;
    const int l15 = lane & 15, l4 = lane >> 4;
    const int cw = wave * 64;                   // channel block
    const char* src = (const char*)P2 + (size_t)tile * 32768;
#pragma unroll
    for (int i = 0; i < 8; ++i) {
        int o = t * 16 + i * 4096;
        *(uint4*)((char*)Ps + o) = *(const uint4*)(src + o);
    }
    __syncthreads();
    f32x4 acc[4][4] = {};
#pragma unroll
    for (int ks = 0; ks < 256; ks += 32) {
        f16x8 w[4], p[4];
#pragma unroll
        for (int mb = 0; mb < 4; ++mb) {
            int c = cw + mb * 16 + l15;
            size_t off = ((((size_t)ks >> 3) + l4) * HID + c) << 3;
            w[mb] = *(const f16x8*)(wp + WCOFF + off);
        }
#pragma unroll
        for (int jb = 0; jb < 4; ++jb) {
            int r = jb * 16 + l15;
            int byte = r * 512 + (ks + l4 * 8) * 2;
            int swz = byte ^ ((r & 7) << 4);
            p[jb] = *(f16x8*)((char*)Ps + swz);
        }
#pragma unroll
        for (int mb = 0; mb < 4; ++mb)
#pragma unroll
            for (int jb = 0; jb < 4; ++jb)
                acc[mb][jb] = __builtin_amdgcn_mfma_f32_16x16x32_f16(w[mb], p[jb], acc[mb][jb], 0, 0, 0);
    }
    const bool full = (row0 + 64 <= NMESH);
#pragma unroll
    for (int mb = 0; mb < 4; ++mb) {
#pragma unroll
        for (int r = 0; r < 4; ++r) {
            int c = cw + mb * 16 + l4 * 4 + r;
            float bv = bc[c];
            float* orow = out + (size_t)c * NMESH + row0;
#pragma unroll
            for (int jb = 0; jb < 4; ++jb) {
                int j = jb * 16 + l15;
                float v = gelu_fast(acc[mb][jb][r] + bv);
                if (full || row0 + j < NMESH) orow[j] = v;
            }
        }
    }
}

extern "C" void kernel_launch(void* const* d_in, const int* in_sizes, int n_in,
                              void* d_out, int out_size, void* d_ws, size_t ws_size,
                              hipStream_t stream) {
    const float* x   = (const float*)d_in[0];
    const int*   ei  = (const int*)d_in[1];
    const int*   Lat = (const int*)d_in[2];
    const int*   Lon = (const int*)d_in[3];
    const float* W1  = (const float*)d_in[4];
    const float* b1  = (const float*)d_in[5];
    const float* W2  = (const float*)d_in[6];
    const float* b2  = (const float*)d_in[7];
    const float* Wl  = (const float*)d_in[8];
    const float* bl  = (const float*)d_in[9];
    const float* Wl1 = (const float*)d_in[10];
    const float* bl1 = (const float*)d_in[11];
    float* out = (float*)d_out;
    const int E = in_sizes[1] / 2;
    const int padmax = E + 3 * NTOT + 4;             // upper bound on padded edges
    const int nfill = (padmax + 255) / 256;

    // d_out scratch: h0 fp16 (NTOT+1 rows incl. phantom) + epk; final_k overwrites.
    f16*   h0  = (f16*)d_out;                        // (NTOT+1)*96 fp16
    int2*  epk = (int2*)((char*)d_out + (size_t)(NTOT + 1) * KPAD1 * 2);

    f16*   P0   = (f16*)d_ws;                        // NT1TILES*6144 f16 (swizzled tiles)
    f16*   Af   = P0 + (size_t)NT1TILES * 6144;      // (NTOT+1)*256 f16 (sigma256 cols)
    f16*   P2   = Af + (size_t)(NTOT + 1) * HID;     // NT2TILES*16384 f16 (swizzled tiles)
    float* deg  = (float*)(P2 + (size_t)NT2TILES * 16384);
    float* dinv = deg + NTOT;
    int*   off  = (int*)(dinv + NTOT);
    int*   cnt  = off + NTOT;
    int*   bsum = cnt + NTOT;                        // 128
    float* M1   = (float*)(bsum + 128);              // 256*256 (Wl@Wl1)
    float* bc   = M1 + HID * HID;                    // 256
    f16*   wp   = (f16*)(bc + HID);                  // WALLK*256 f16 packed

    // 1. mega: transpose x | deg/cnt init | epk dummy fill | phantom zero rows
    transpose_x<<<TXBLKS + DEGBLKS + nfill + 1, 256, 0, stream>>>(
        x, h0, deg, cnt, epk,
        (unsigned*)(h0 + (size_t)NTOT * KPAD1),
        (unsigned*)(Af + (size_t)NTOT * HID), padmax);
    mesh_interp<<<(NMESH * 48 + 255) / 256, 256, 0, stream>>>(h0, Lat, Lon,
                                                              h0 + (size_t)NGRID * KPAD1);

    // 2. degree / norm / padded CSR
    deg_scatter<<<(E + 255) / 256, 256, 0, stream>>>(ei, deg, E);
    scan1<<<NBLK_SCAN, SCAN_BS, 0, stream>>>(deg, dinv, off, bsum);
    scan3<<<NBLK_SCAN, SCAN_BS, 0, stream>>>(off, bsum);
    csr_fill<<<(E + 255) / 256, 256, 0, stream>>>(ei, dinv, off, cnt, epk, E);

    // 2b. weight collapse: M1 = Wl@Wl1; then Wc packed + W1 packed + bc in one kernel
    dim3 gW(4, 4);
    wgemm<<<gW, 256, 0, stream>>>(Wl, Wl1, M1);
    finish_w<<<113, 256, 0, stream>>>(W2, M1, W1, b2, bl, Wl1, bl1, wp, bc);

    // 3. layer 1: padded weighted aggregate -> P0, then wave-per-stripe GEMM
    agg1<<<(int)(((long long)NT1PAD * 64 + 255) / 256), 256, 0, stream>>>(
        h0, deg, dinv, off, epk, P0);
    gemm1_f16<<<(NT1TILES * 8 * 64 + 255) / 256, 256, 0, stream>>>(P0, wp, b1, Af);

    // 4. layer 2 aggregation (mesh dsts only) -> P2
    agg2<<<(int)(((long long)NT2PAD * 64 + 255) / 256), 256, 0, stream>>>(
        Af, deg, dinv, off, epk, P2);

    // 5. collapsed tail: out = gelu(Wc^T @ P2^T + bc), written directly transposed
    final_k<<<NT2TILES, 256, 0, stream>>>(P2, wp, bc, out);
}